// Round 8
// baseline (12234.259 us; speedup 1.0000x reference)
//
#include <hip/hip_runtime.h>

#define DEV __device__ __forceinline__

namespace {
constexpr int Bc = 32;
constexpr int Tc = 256;
constexpr int Dc = 512;
constexpr int NBLK = 256;
constexpr int NW   = 128;          // writer blocks (own 16 mem rows each)
constexpr int ROWS = 16;

// workspace layout (float offsets)
constexpr size_t OFF_KN   = 0;                                  // [T][B][D] normalized k
constexpr size_t OFF_E    = OFF_KN + (size_t)Tc * Bc * Dc;      // [T][B][D] sigmoid(erase)
constexpr size_t OFF_A    = OFF_E  + (size_t)Tc * Bc * Dc;      // [T][B][D] add
constexpr size_t OFF_RP   = OFF_A  + (size_t)Tc * Bc * Dc;      // [2][NW][B][D] bf16 read partials
constexpr size_t OFF_DENP = OFF_RP + (size_t)2 * NW * Bc * Dc;  // [2][NW][B] den partials
constexpr size_t OFF_FLAGS= OFF_DENP + (size_t)2 * NW * Bc;     // 256*16 u32 arrival flags
}

DEV float sigm(float x) { return 1.0f / (1.0f + __expf(-x)); }

// Agent-scope relaxed helpers (proven coherent across XCDs in R3-R6).
DEV float ld1cg(const float* p) {
  unsigned u = __hip_atomic_load((const unsigned*)p, __ATOMIC_RELAXED,
                                 __HIP_MEMORY_SCOPE_AGENT);
  return __uint_as_float(u);
}
DEV void st1cg(float* p, float v) {
  __hip_atomic_store((unsigned*)p, __float_as_uint(v), __ATOMIC_RELAXED,
                     __HIP_MEMORY_SCOPE_AGENT);
}
DEV unsigned long long ld8cg(const unsigned long long* p) {
  return __hip_atomic_load(p, __ATOMIC_RELAXED, __HIP_MEMORY_SCOPE_AGENT);
}
DEV void st8cg(unsigned long long* p, unsigned long long v) {
  __hip_atomic_store(p, v, __ATOMIC_RELAXED, __HIP_MEMORY_SCOPE_AGENT);
}

DEV unsigned pack_bf2(float x, float y) {   // RNE f32->bf16 pair
  unsigned ux = __float_as_uint(x), uy = __float_as_uint(y);
  unsigned rx = (ux + 0x7FFFu + ((ux >> 16) & 1u)) >> 16;
  unsigned ry = (uy + 0x7FFFu + ((uy >> 16) & 1u)) >> 16;
  return rx | (ry << 16);
}
DEV float lo16f(unsigned u) { return __uint_as_float(u << 16); }
DEV float hi16f(unsigned u) { return __uint_as_float(u & 0xFFFF0000u); }

// ---------------------------------------------------------------------------
// K1: 4 fused controller GEMMs (unchanged, validated).
// ---------------------------------------------------------------------------
__global__ __launch_bounds__(256) void k_gemm(
    const float* __restrict__ A,
    const float* __restrict__ Wk, const float* __restrict__ bk,
    const float* __restrict__ We, const float* __restrict__ be,
    const float* __restrict__ Ww, const float* __restrict__ bw,
    const float* __restrict__ Wg, const float* __restrict__ bg,
    float* __restrict__ ws, float* __restrict__ gout)
{
  __shared__ float As[32][68];
  __shared__ float Bs[32][68];

  const int bid = blockIdx.x;
  const int mat = bid >> 10;
  const int rem = bid & 1023;
  const int rt = rem >> 3, jt = rem & 7;
  const int rbase = rt * 64, jbase = jt * 64;

  const float* Wm; const float* bm;
  if      (mat == 0) { Wm = Wk; bm = bk; }
  else if (mat == 1) { Wm = We; bm = be; }
  else if (mat == 2) { Wm = Ww; bm = bw; }
  else               { Wm = Wg; bm = bg; }

  const int tid = threadIdx.x;
  const int lr = tid >> 2;
  const int lk = (tid & 3) * 8;
  const int ty = tid >> 4, tx = tid & 15;

  float acc[4][4] = {};

  for (int k0 = 0; k0 < Dc; k0 += 32) {
    const float4 a0 = *(const float4*)&A [(size_t)(rbase + lr) * Dc + k0 + lk];
    const float4 a1 = *(const float4*)&A [(size_t)(rbase + lr) * Dc + k0 + lk + 4];
    const float4 b0 = *(const float4*)&Wm[(size_t)(jbase + lr) * Dc + k0 + lk];
    const float4 b1 = *(const float4*)&Wm[(size_t)(jbase + lr) * Dc + k0 + lk + 4];
    __syncthreads();
    As[lk + 0][lr] = a0.x; As[lk + 1][lr] = a0.y; As[lk + 2][lr] = a0.z; As[lk + 3][lr] = a0.w;
    As[lk + 4][lr] = a1.x; As[lk + 5][lr] = a1.y; As[lk + 6][lr] = a1.z; As[lk + 7][lr] = a1.w;
    Bs[lk + 0][lr] = b0.x; Bs[lk + 1][lr] = b0.y; Bs[lk + 2][lr] = b0.z; Bs[lk + 3][lr] = b0.w;
    Bs[lk + 4][lr] = b1.x; Bs[lk + 5][lr] = b1.y; Bs[lk + 6][lr] = b1.z; Bs[lk + 7][lr] = b1.w;
    __syncthreads();
    #pragma unroll
    for (int kk = 0; kk < 32; ++kk) {
      const float4 av = *(const float4*)&As[kk][ty * 4];
      const float4 bv = *(const float4*)&Bs[kk][tx * 4];
      const float ar[4] = {av.x, av.y, av.z, av.w};
      const float br[4] = {bv.x, bv.y, bv.z, bv.w};
      #pragma unroll
      for (int i = 0; i < 4; ++i)
        #pragma unroll
        for (int j = 0; j < 4; ++j)
          acc[i][j] = fmaf(ar[i], br[j], acc[i][j]);
    }
  }

  const float4 bias = *(const float4*)&bm[jbase + tx * 4];
  const float bi[4] = {bias.x, bias.y, bias.z, bias.w};
  #pragma unroll
  for (int i = 0; i < 4; ++i) {
    const int r = rbase + ty * 4 + i;
    float v[4];
    #pragma unroll
    for (int j = 0; j < 4; ++j) {
      v[j] = acc[i][j] + bi[j];
      if (mat & 1) v[j] = sigm(v[j]);
    }
    float4 o; o.x = v[0]; o.y = v[1]; o.z = v[2]; o.w = v[3];
    if (mat == 3) {
      *(float4*)&gout[(size_t)r * Dc + jbase + tx * 4] = o;   // g -> d_out (temp)
    } else {
      float* dst = ws + (mat == 0 ? OFF_KN : (mat == 1 ? OFF_E : OFF_A));
      const int t = r & 255, b = r >> 8;                      // r = b*T + t
      *(float4*)&dst[((size_t)t * Bc + b) * Dc + jbase + tx * 4] = o;
    }
  }
}

// ---------------------------------------------------------------------------
// K2: l2-normalize k rows in place (unchanged).
// ---------------------------------------------------------------------------
__global__ __launch_bounds__(256) void k_knorm(float* __restrict__ kn)
{
  const int row = blockIdx.x * 4 + (threadIdx.x >> 6);
  const int lane = threadIdx.x & 63;
  float* p = kn + (size_t)row * Dc;
  float4 v0 = *(const float4*)&p[lane * 4];
  float4 v1 = *(const float4*)&p[256 + lane * 4];
  float ss = v0.x*v0.x + v0.y*v0.y + v0.z*v0.z + v0.w*v0.w
           + v1.x*v1.x + v1.y*v1.y + v1.z*v1.z + v1.w*v1.w;
  #pragma unroll
  for (int off = 32; off >= 1; off >>= 1) ss += __shfl_xor(ss, off);
  const float inv = 1.0f / fmaxf(sqrtf(ss), 1e-12f);
  v0.x *= inv; v0.y *= inv; v0.z *= inv; v0.w *= inv;
  v1.x *= inv; v1.y *= inv; v1.z *= inv; v1.w *= inv;
  *(float4*)&p[lane * 4] = v0;
  *(float4*)&p[256 + lane * 4] = v1;
}

// ---------------------------------------------------------------------------
// Single-hop all-to-all barrier (R6, proven).
// ---------------------------------------------------------------------------
DEV void gbar(unsigned* flags, unsigned step, int bid, int tid)
{
  __syncthreads();                 // all waves drain vmcnt -> stores coherent
  if (tid == 0)
    __hip_atomic_store(&flags[bid * 16], step, __ATOMIC_RELAXED,
                       __HIP_MEMORY_SCOPE_AGENT);
  while (__hip_atomic_load(&flags[tid * 16], __ATOMIC_RELAXED,
                           __HIP_MEMORY_SCOPE_AGENT) < step)
    __builtin_amdgcn_s_sleep(1);
  __syncthreads();
}

// ---------------------------------------------------------------------------
// sim phase: y = block's 16 memory rows (LDS); kn read cached (read-only).
// ---------------------------------------------------------------------------
DEV void sim_phase(const float* __restrict__ knp, float* __restrict__ denp_row,
                   const float (*y)[516], float* __restrict__ ew_own,
                   const float* invn_s, float* sred, int tid)
{
  const int r = tid >> 4, bp = tid & 15;
  const float* k0p = knp + (size_t)bp * Dc;
  const float* k1p = knp + (size_t)(bp + 16) * Dc;
  float acc0 = 0.f, acc1 = 0.f;
  #pragma unroll 4
  for (int dq = 0; dq < Dc / 4; ++dq) {
    const float4 y4 = *(const float4*)&y[r][dq * 4];
    const float4 ka = *(const float4*)&k0p[dq * 4];
    const float4 kb = *(const float4*)&k1p[dq * 4];
    acc0 = fmaf(y4.x, ka.x, acc0); acc0 = fmaf(y4.y, ka.y, acc0);
    acc0 = fmaf(y4.z, ka.z, acc0); acc0 = fmaf(y4.w, ka.w, acc0);
    acc1 = fmaf(y4.x, kb.x, acc1); acc1 = fmaf(y4.y, kb.y, acc1);
    acc1 = fmaf(y4.z, kb.z, acc1); acc1 = fmaf(y4.w, kb.w, acc1);
  }
  const float iv = invn_s[r];
  const float e0 = __expf(acc0 * iv);
  const float e1 = __expf(acc1 * iv);
  ew_own[r * 32 + bp]      = e0;
  ew_own[r * 32 + bp + 16] = e1;
  if (tid < 32) sred[tid] = 0.f;
  __syncthreads();
  atomicAdd(&sred[bp], e0);            // LDS atomics (block-local)
  atomicAdd(&sred[bp + 16], e1);
  __syncthreads();
  if (tid < 32) st1cg(&denp_row[tid], sred[tid]);
}

// ---------------------------------------------------------------------------
// Persistent recurrent kernel, 256 blocks (1 block/CU).
// ---------------------------------------------------------------------------
__global__ __launch_bounds__(256, 1) void k_main(
    const float* __restrict__ cs, const float* __restrict__ mem_in,
    const float* __restrict__ gamma, const float* __restrict__ beta,
    float* __restrict__ ws, float* __restrict__ out)
{
  __shared__ float    mrows[16][516];   // persistent memory rows (W)
  __shared__ unsigned sbuf[32][256];    // rp bf16 bounce: [b][colpair]
  __shared__ float    ew_own[16 * 32];
  __shared__ float    wbuf[16][32];
  __shared__ float    lds_red[256];
  __shared__ float    redR[16][128];    // reducer col reduce
  __shared__ float    sred[32];
  __shared__ float    mu_s[16], rs_s[16], invn_s[16], dinv_s[32];

  float* kn   = ws + OFF_KN;
  float* eptb = ws + OFF_E;
  float* aptb = ws + OFF_A;
  unsigned long long* rp64_all = (unsigned long long*)(ws + OFF_RP);
  float* denp = ws + OFF_DENP;
  unsigned* flags = (unsigned*)(ws + OFF_FLAGS);

  const int bid = blockIdx.x, tid = threadIdx.x;
  const float inv32 = 1.0f / 32.0f;
  const size_t RPPAR = (size_t)NW * Bc * (Dc / 4);   // u64s per parity

  float2 ev[32], av[32];   // e[t]/a[t] resident registers (W)

  if (bid < NW) {
    const int s0 = bid * ROWS;
    const int c0 = tid * 2;
    #pragma unroll
    for (int r = 0; r < ROWS; ++r)
      *(float2*)&mrows[r][c0] = *(const float2*)&mem_in[(size_t)(s0 + r) * Dc + c0];
    #pragma unroll
    for (int b = 0; b < 32; ++b) {
      ev[b] = *(const float2*)&eptb[(size_t)b * Dc + c0];
      av[b] = *(const float2*)&aptb[(size_t)b * Dc + c0];
    }
    __syncthreads();
    {
      const int row = tid >> 4, li = tid & 15;
      float ss = 0.f;
      #pragma unroll
      for (int i = 0; i < 8; ++i) {
        const float4 v = *(const float4*)&mrows[row][(li + i * 16) * 4];
        ss += v.x*v.x + v.y*v.y + v.z*v.z + v.w*v.w;
      }
      ss += __shfl_xor(ss, 8); ss += __shfl_xor(ss, 4);
      ss += __shfl_xor(ss, 2); ss += __shfl_xor(ss, 1);
      if (li == 0) invn_s[row] = 1.0f / fmaxf(sqrtf(ss), 1e-12f);
    }
    __syncthreads();
    sim_phase(kn, denp + (size_t)bid * Bc, mrows, ew_own, invn_s, sred, tid);
  }
  gbar(flags, 1u, bid, tid);

  for (int t = 0; t <= Tc; ++t) {
    if (bid < NW) {
      if (t < Tc) {
        const int c0 = tid * 2;
        // 1) den agg from 128 partials (parity t&1) — R6 code, proven
        {
          const float* dp = denp + (size_t)(t & 1) * NW * Bc;
          const int b = tid & 31, ch = tid >> 5;
          float s = 0.f;
          #pragma unroll
          for (int g = 0; g < 16; ++g)
            s += ld1cg(&dp[(size_t)(ch * 16 + g) * Bc + b]);
          lds_red[tid] = s;
          __syncthreads();
          if (tid < 32) {
            float tot = 0.f;
            #pragma unroll
            for (int c2 = 0; c2 < 8; ++c2) tot += lds_red[c2 * 32 + tid];
            dinv_s[tid] = 1.0f / tot;
          }
          __syncthreads();
        }
        // 2) normalized weights for own rows
        for (int idx = tid; idx < ROWS * 32; idx += 256)
          wbuf[idx >> 5][idx & 31] = ew_own[idx] * dinv_s[idx & 31];
        __syncthreads();

        // 3) read partial -> bf16 bounce -> 8B coherent stores (4 cols each)
        float2 mr[ROWS];
        #pragma unroll
        for (int r = 0; r < ROWS; ++r) mr[r] = *(const float2*)&mrows[r][c0];
        #pragma unroll 4
        for (int b = 0; b < 32; ++b) {
          float2 a; a.x = 0.f; a.y = 0.f;
          #pragma unroll
          for (int r = 0; r < ROWS; ++r) {
            const float wv = wbuf[r][b];
            a.x = fmaf(wv, mr[r].x, a.x);
            a.y = fmaf(wv, mr[r].y, a.y);
          }
          sbuf[b][tid] = pack_bf2(a.x, a.y);
        }
        __syncthreads();
        {
          unsigned long long* rp64 = rp64_all + (size_t)(t & 1) * RPPAR
                                   + (size_t)bid * Bc * (Dc / 4);
          #pragma unroll
          for (int i = 0; i < 16; ++i) {
            const int idx = tid + i * 256;          // 0..4095
            const int b = idx >> 7, dq = idx & 127; // cols 4dq..4dq+3
            const unsigned long long v =
                (unsigned long long)sbuf[b][dq * 2]
              | ((unsigned long long)sbuf[b][dq * 2 + 1] << 32);
            st8cg(&rp64[(size_t)b * (Dc / 4) + dq], v);
          }
        }

        if (t < Tc - 1) {
          // 4) erase/add from resident registers
          float2 er[ROWS] = {}, ad[ROWS] = {};
          #pragma unroll
          for (int b = 0; b < 32; ++b) {
            const float2 e2 = ev[b], a2 = av[b];
            #pragma unroll
            for (int r = 0; r < ROWS; ++r) {
              const float wv = wbuf[r][b];
              er[r].x = fmaf(wv, e2.x, er[r].x); er[r].y = fmaf(wv, e2.y, er[r].y);
              ad[r].x = fmaf(wv, a2.x, ad[r].x); ad[r].y = fmaf(wv, a2.y, ad[r].y);
            }
          }
          float2 xr[ROWS];
          #pragma unroll
          for (int r = 0; r < ROWS; ++r) {
            float2 x;
            x.x = mr[r].x * (1.0f - er[r].x * inv32) + ad[r].x * inv32;
            x.y = mr[r].y * (1.0f - er[r].y * inv32) + ad[r].y * inv32;
            xr[r] = x;
            *(float2*)&mrows[r][c0] = x;
          }
          // 5) prefetch e/a for t+1
          if (t <= Tc - 3) {
            const float* ep1 = eptb + (size_t)(t + 1) * Bc * Dc;
            const float* ap1 = aptb + (size_t)(t + 1) * Bc * Dc;
            #pragma unroll
            for (int b = 0; b < 32; ++b) {
              ev[b] = *(const float2*)&ep1[(size_t)b * Dc + c0];
              av[b] = *(const float2*)&ap1[(size_t)b * Dc + c0];
            }
          }
          __syncthreads();
          // 6) LN stats
          {
            const int row = tid >> 4, li = tid & 15;
            float s1 = 0.f, s2 = 0.f;
            #pragma unroll
            for (int i = 0; i < 8; ++i) {
              const float4 v = *(const float4*)&mrows[row][(li + i * 16) * 4];
              s1 += v.x + v.y + v.z + v.w;
              s2 += v.x*v.x + v.y*v.y + v.z*v.z + v.w*v.w;
            }
            s1 += __shfl_xor(s1, 8); s2 += __shfl_xor(s2, 8);
            s1 += __shfl_xor(s1, 4); s2 += __shfl_xor(s2, 4);
            s1 += __shfl_xor(s1, 2); s2 += __shfl_xor(s2, 2);
            s1 += __shfl_xor(s1, 1); s2 += __shfl_xor(s2, 1);
            if (li == 0) {
              const float mu = s1 * (1.0f / 512.0f);
              const float var = s2 * (1.0f / 512.0f) - mu * mu;
              mu_s[row] = mu;
              rs_s[row] = rsqrtf(var + 1e-5f);
            }
          }
          __syncthreads();
          const float2 gm  = *(const float2*)&gamma[c0];
          const float2 bt2 = *(const float2*)&beta[c0];
          #pragma unroll
          for (int r = 0; r < ROWS; ++r) {
            const float mu = mu_s[r], rs = rs_s[r];
            float2 y;
            y.x = (xr[r].x - mu) * rs * gm.x + bt2.x;
            y.y = (xr[r].y - mu) * rs * gm.y + bt2.y;
            *(float2*)&mrows[r][c0] = y;
          }
          __syncthreads();
          // 7) row l2 norms
          {
            const int row = tid >> 4, li = tid & 15;
            float ss = 0.f;
            #pragma unroll
            for (int i = 0; i < 8; ++i) {
              const float4 v = *(const float4*)&mrows[row][(li + i * 16) * 4];
              ss += v.x*v.x + v.y*v.y + v.z*v.z + v.w*v.w;
            }
            ss += __shfl_xor(ss, 8); ss += __shfl_xor(ss, 4);
            ss += __shfl_xor(ss, 2); ss += __shfl_xor(ss, 1);
            if (li == 0) invn_s[row] = 1.0f / fmaxf(sqrtf(ss), 1e-12f);
          }
          __syncthreads();
          // 8) sim for t+1
          sim_phase(kn + (size_t)(t + 1) * Bc * Dc,
                    denp + (size_t)((t + 1) & 1) * NW * Bc + (size_t)bid * Bc,
                    mrows, ew_own, invn_s, sred, tid);
        }
      }
    } else {
      // Reducer: out for step t-1 from bf16 packed rp.
      if (t >= 1) {
        const int t0 = t - 1;
        const int rb = bid - NW;
        const int b = rb >> 2;
        const int d0 = (rb & 3) * 128;
        const unsigned long long* rp64 = rp64_all + (size_t)(t0 & 1) * RPPAR;
        const int pg = tid >> 4;           // 0..15: partial group (8 partials)
        const int cq = tid & 15;           // 0..15: colgroup of 8 cols
        const size_t cofs = (size_t)(d0 + cq * 8) / 4;
        float acc[8] = {};
        #pragma unroll
        for (int i = 0; i < 8; ++i) {
          const int p = pg * 8 + i;
          const size_t base = ((size_t)p * Bc + b) * (Dc / 4) + cofs;
          const unsigned long long v0 = ld8cg(&rp64[base]);
          const unsigned long long v1 = ld8cg(&rp64[base + 1]);
          const unsigned u0 = (unsigned)v0, u1 = (unsigned)(v0 >> 32);
          const unsigned u2 = (unsigned)v1, u3 = (unsigned)(v1 >> 32);
          acc[0] += lo16f(u0); acc[1] += hi16f(u0);
          acc[2] += lo16f(u1); acc[3] += hi16f(u1);
          acc[4] += lo16f(u2); acc[5] += hi16f(u2);
          acc[6] += lo16f(u3); acc[7] += hi16f(u3);
        }
        #pragma unroll
        for (int j = 0; j < 8; ++j) redR[pg][cq * 8 + j] = acc[j];
        __syncthreads();
        if (tid < 128) {
          float s = 0.f;
          #pragma unroll
          for (int p = 0; p < 16; ++p) s += redR[p][tid];
          const size_t oofs = ((size_t)b * Tc + t0) * Dc + d0 + tid;
          const float g  = out[oofs];
          const float cv = cs[oofs];
          out[oofs] = g * cv + (1.0f - g) * s;
        }
        __syncthreads();
      }
    }
    if (t < Tc) gbar(flags, (unsigned)(t + 2), bid, tid);
  }
}

// ---------------------------------------------------------------------------
extern "C" void kernel_launch(void* const* d_in, const int* in_sizes, int n_in,
                              void* d_out, int out_size, void* d_ws, size_t ws_size,
                              hipStream_t stream)
{
  const float* cs    = (const float*)d_in[0];
  const float* mem   = (const float*)d_in[1];
  const float* Wk    = (const float*)d_in[2];
  const float* bk    = (const float*)d_in[3];
  const float* We    = (const float*)d_in[4];
  const float* be    = (const float*)d_in[5];
  const float* Ww    = (const float*)d_in[6];
  const float* bw    = (const float*)d_in[7];
  const float* Wg    = (const float*)d_in[8];
  const float* bg    = (const float*)d_in[9];
  const float* gamma = (const float*)d_in[10];
  const float* beta  = (const float*)d_in[11];
  float* ws  = (float*)d_ws;
  float* out = (float*)d_out;

  // zero barrier flags
  hipMemsetAsync(ws + OFF_FLAGS, 0, 256 * 16 * sizeof(unsigned), stream);

  hipLaunchKernelGGL(k_gemm, dim3(4096), dim3(256), 0, stream,
                     cs, Wk, bk, We, be, Ww, bw, Wg, bg, ws, out);
  hipLaunchKernelGGL(k_knorm, dim3(2048), dim3(256), 0, stream, ws + OFF_KN);
  hipLaunchKernelGGL(k_main, dim3(NBLK), dim3(256), 0, stream,
                     cs, mem, gamma, beta, ws, out);
}